// Round 3
// baseline (474.723 us; speedup 1.0000x reference)
//
#include <hip/hip_runtime.h>
#include <hip/hip_bf16.h>

#define NN 512
#define NSTEPS 5

typedef __attribute__((ext_vector_type(8))) short short8;
typedef __attribute__((ext_vector_type(4))) float floatx4;

static __device__ __forceinline__ unsigned short f2bf(float f) {
    union { float f; unsigned u; } x; x.f = f;
    unsigned r = x.u + 0x7fffu + ((x.u >> 16) & 1u);
    return (unsigned short)(r >> 16);
}

static __device__ __forceinline__ unsigned pk2bf(float a, float b) {
    __hip_bfloat162 h = __float22bfloat162_rn(make_float2(a, b));
    return *reinterpret_cast<unsigned*>(&h);
}

#define FLAG_STRIDE 32   // ints: 128B per flag -> one L2 line each, zero contention

// Tree barrier: per-block arrive flag -> block0 collects -> per-block go flag.
// Flags are epoch-valued (monotone, start at 0 via host memset).
// __threadfence() provides cross-XCD data visibility (wbl2 / inv).
static __device__ __forceinline__ void fast_grid_barrier(
    int* __restrict__ arrive, int* __restrict__ go,
    int epoch, int bid, int tid)
{
    __threadfence();          // release: flush this XCD's L2 (aOut stores)
    __syncthreads();
    if (bid == 0) {
        if (tid < 256) {
            if (tid == 0)
                __hip_atomic_store(&arrive[0], epoch, __ATOMIC_RELAXED, __HIP_MEMORY_SCOPE_AGENT);
            while (__hip_atomic_load(&arrive[tid*FLAG_STRIDE], __ATOMIC_RELAXED, __HIP_MEMORY_SCOPE_AGENT) < epoch)
                __builtin_amdgcn_s_sleep(2);
            __hip_atomic_store(&go[tid*FLAG_STRIDE], epoch, __ATOMIC_RELAXED, __HIP_MEMORY_SCOPE_AGENT);
        }
    } else {
        if (tid == 0) {
            __hip_atomic_store(&arrive[bid*FLAG_STRIDE], epoch, __ATOMIC_RELAXED, __HIP_MEMORY_SCOPE_AGENT);
            while (__hip_atomic_load(&go[bid*FLAG_STRIDE], __ATOMIC_RELAXED, __HIP_MEMORY_SCOPE_AGENT) < epoch)
                __builtin_amdgcn_s_sleep(2);
        }
    }
    __syncthreads();
    __threadfence();          // acquire: invalidate this XCD's L2 before aIn reads
}

// ============================================================================
// Cooperative fused kernel: 256 blocks x 512 threads, 2 nodes per block.
// Custom contention-free grid barrier instead of cg::grid_group::sync().
// ============================================================================
__global__ __launch_bounds__(512, 2) void fused2_kernel(
    const float* __restrict__ J, const float* __restrict__ b,
    const float* __restrict__ W1, const float* __restrict__ b1,
    const float* __restrict__ W2, const float* __restrict__ b2,
    const float* __restrict__ W3, const float* __restrict__ b3,
    const float* __restrict__ W_ih, const float* __restrict__ b_ih,
    const float* __restrict__ W_hh, const float* __restrict__ b_hh,
    const float* __restrict__ Wr1, const float* __restrict__ br1,
    const float* __restrict__ Wr2, const float* __restrict__ br2,
    const float* __restrict__ Wr3, const float* __restrict__ br3,
    float* __restrict__ aBuf0, float* __restrict__ aBuf1,
    int* __restrict__ flags,
    float* __restrict__ out)
{
    const int tid = threadIdx.x;
    const int bid = blockIdx.x;
    const int nd = tid >> 8;          // which of the block's 2 nodes
    const int tl = tid & 255;         // local tid within node group
    const int j  = bid * 2 + nd;
    const int l  = tid & 63, w4 = tl >> 6;
    const int m  = l & 15,  q  = l >> 4;

    int* arrive = flags;
    int* go     = flags + 256*FLAG_STRIDE;

    __shared__ float smW1hi[64][16], smW1hj[64][16];
    __shared__ float smC[2][64], smAbias[2][64], smCbias[2][64];
    __shared__ float smWave[2][4][64], smMacc[2][64];
    __shared__ float smGin[2][48], smGi[2][48], smGh[2][48];
    __shared__ float smH[2][16], smY[2][64], smR[2][2];

    // ---- one-time init ----
    if (tid < 64) {
        const float* w1r = W1 + tid*35;
        #pragma unroll
        for (int s = 0; s < 16; ++s) {
            smW1hi[tid][s] = w1r[s];
            smW1hj[tid][s] = w1r[16 + s];
        }
    }
    if (tid < 128) {
        int nd0 = tid >> 6, o = tid & 63;
        int j0 = bid*2 + nd0;
        float bj0 = b[j0];
        const float* w1r = W1 + o*35;
        float ab = bj0 * w1r[33];
        smAbias[nd0][o] = ab;
        float cb = bj0 * w1r[34] + b1[o];
        smCbias[nd0][o] = cb;
        smC[nd0][o] = cb;                  // h0 = 0 -> c0 bias-only
        aBuf0[j0*64 + o] = ab;             // h0 = 0 -> a0 bias-only
    }
    if (tid >= 128 && tid < 160) {
        int nd0 = (tid - 128) >> 4, o = (tid - 128) & 15;
        smH[nd0][o] = 0.f;
    }

    // J column for this node (i = w4*128 + c8*16 + m), once
    float Jr[8];
    #pragma unroll
    for (int c8 = 0; c8 < 8; ++c8)
        Jr[c8] = J[(w4*128 + c8*16 + m)*512 + j];

    // wJ vectors for this lane's o-set
    floatx4 wva, wvb, wvc, wvd;
    #pragma unroll
    for (int e = 0; e < 4; ++e) {
        wva[e] = W1[(q*8 + e)*35 + 32];
        wvb[e] = W1[(q*8 + 4 + e)*35 + 32];
        wvc[e] = W1[(32 + q*8 + e)*35 + 32];
        wvd[e] = W1[(32 + q*8 + 4 + e)*35 + 32];
    }

    // W2 B-fragments, in-register, once. B[k][n] = W2[n][k]
    short8 bfw[4][2];
    #pragma unroll
    for (int nt = 0; nt < 4; ++nt) {
        #pragma unroll
        for (int ks = 0; ks < 2; ++ks) {
            union { short8 s; unsigned short us[8]; } tpk;
            int n = nt*16 + m;
            #pragma unroll
            for (int jj = 0; jj < 8; ++jj)
                tpk.us[jj] = f2bf(W2[n*64 + ks*32 + q*8 + jj]);
            bfw[nt][ks] = tpk.s;
        }
    }
    float b2n[4];
    #pragma unroll
    for (int nt = 0; nt < 4; ++nt) b2n[nt] = b2[nt*16 + m];

    fast_grid_barrier(arrive, go, 1, bid, tid);   // a0 visible grid-wide

    float* aIn = aBuf0;
    float* aOut = aBuf1;

    for (int t = 0; t < NSTEPS; ++t) {
        const int last = (t == NSTEPS - 1);

        floatx4 cva, cvb, cvc, cvd;
        #pragma unroll
        for (int e = 0; e < 4; ++e) {
            cva[e] = smC[nd][q*8 + e];
            cvb[e] = smC[nd][q*8 + 4 + e];
            cvc[e] = smC[nd][32 + q*8 + e];
            cvd[e] = smC[nd][32 + q*8 + 4 + e];
        }

        floatx4 acc[4];
        #pragma unroll
        for (int nt = 0; nt < 4; ++nt) acc[nt] = (floatx4){0.f,0.f,0.f,0.f};

        const floatx4* a4 = (const floatx4*)aIn;

        for (int c8 = 0; c8 < 8; ++c8) {
            int i = w4*128 + c8*16 + m;
            float Jij = Jr[c8];
            floatx4 av0 = a4[i*16 + q*2],     av1 = a4[i*16 + q*2 + 1];
            floatx4 av2 = a4[i*16 + 8 + q*2], av3 = a4[i*16 + 8 + q*2 + 1];
            floatx4 x0, x1, x2, x3;
            #pragma unroll
            for (int e = 0; e < 4; ++e) {
                x0[e] = fmaxf(fmaf(Jij, wva[e], av0[e]) + cva[e], 0.f);
                x1[e] = fmaxf(fmaf(Jij, wvb[e], av1[e]) + cvb[e], 0.f);
                x2[e] = fmaxf(fmaf(Jij, wvc[e], av2[e]) + cvc[e], 0.f);
                x3[e] = fmaxf(fmaf(Jij, wvd[e], av3[e]) + cvd[e], 0.f);
            }
            union { short8 s; unsigned u[4]; } fa0, fa1;
            fa0.u[0] = pk2bf(x0[0], x0[1]); fa0.u[1] = pk2bf(x0[2], x0[3]);
            fa0.u[2] = pk2bf(x1[0], x1[1]); fa0.u[3] = pk2bf(x1[2], x1[3]);
            fa1.u[0] = pk2bf(x2[0], x2[1]); fa1.u[1] = pk2bf(x2[2], x2[3]);
            fa1.u[2] = pk2bf(x3[0], x3[1]); fa1.u[3] = pk2bf(x3[2], x3[3]);
            #pragma unroll
            for (int nt = 0; nt < 4; ++nt) {
                floatx4 d = {0.f,0.f,0.f,0.f};
                d = __builtin_amdgcn_mfma_f32_16x16x32_bf16(fa0.s, bfw[nt][0], d, 0, 0, 0);
                d = __builtin_amdgcn_mfma_f32_16x16x32_bf16(fa1.s, bfw[nt][1], d, 0, 0, 0);
                #pragma unroll
                for (int r = 0; r < 4; ++r)
                    acc[nt][r] += fmaxf(d[r] + b2n[nt], 0.f);
            }
        }

        // reduce rows within wave, stage h into smGin
        #pragma unroll
        for (int nt = 0; nt < 4; ++nt) {
            float v = acc[nt][0] + acc[nt][1] + acc[nt][2] + acc[nt][3];
            v += __shfl_xor(v, 16);
            v += __shfl_xor(v, 32);
            if (l < 16) smWave[nd][w4][nt*16 + l] = v;
        }
        if (tl < 16) smGin[nd][tl] = smH[nd][tl];
        __syncthreads();
        if (tl < 64) smMacc[nd][tl] = smWave[nd][0][tl] + smWave[nd][1][tl]
                                    + smWave[nd][2][tl] + smWave[nd][3][tl];
        __syncthreads();

        // msg = W3 @ macc + 512*b3
        {
            int o = tl >> 3, p = tl & 7;
            const floatx4* W3v = (const floatx4*)W3;
            floatx4 wv0 = W3v[o*16 + p*2], wv1 = W3v[o*16 + p*2 + 1];
            float part = 0.f;
            #pragma unroll
            for (int e = 0; e < 4; ++e) {
                part = fmaf(wv0[e], smMacc[nd][p*8 + e], part);
                part = fmaf(wv1[e], smMacc[nd][p*8 + 4 + e], part);
            }
            part += __shfl_xor(part, 1);
            part += __shfl_xor(part, 2);
            part += __shfl_xor(part, 4);
            if (p == 0) smGin[nd][16 + o] = part + 512.f * b3[o];
        }
        __syncthreads();

        // GRU gates
        if (tl < 192) {
            int o = tl >> 2, p = tl & 3;
            const floatx4* Wv = (const floatx4*)W_ih;
            floatx4 w0 = Wv[o*12 + p*3], w1 = Wv[o*12 + p*3 + 1], w2 = Wv[o*12 + p*3 + 2];
            int k0 = p*12;
            float part = 0.f;
            #pragma unroll
            for (int e = 0; e < 4; ++e) {
                part = fmaf(w0[e], smGin[nd][k0 + e], part);
                part = fmaf(w1[e], smGin[nd][k0 + 4 + e], part);
                part = fmaf(w2[e], smGin[nd][k0 + 8 + e], part);
            }
            part += __shfl_xor(part, 1);
            part += __shfl_xor(part, 2);
            if (p == 0) smGi[nd][o] = part + b_ih[o];
        } else if (tl < 240) {
            int o = tl - 192;
            const floatx4* Wv = (const floatx4*)W_hh;
            floatx4 w0 = Wv[o*4], w1 = Wv[o*4+1], w2 = Wv[o*4+2], w3 = Wv[o*4+3];
            float s2 = b_hh[o];
            #pragma unroll
            for (int e = 0; e < 4; ++e) {
                s2 = fmaf(w0[e], smGin[nd][e],      s2);
                s2 = fmaf(w1[e], smGin[nd][4 + e],  s2);
                s2 = fmaf(w2[e], smGin[nd][8 + e],  s2);
                s2 = fmaf(w3[e], smGin[nd][12 + e], s2);
            }
            smGh[nd][o] = s2;
        }
        __syncthreads();

        if (tl < 16) {
            float r = 1.f / (1.f + __expf(-(smGi[nd][tl] + smGh[nd][tl])));
            float z = 1.f / (1.f + __expf(-(smGi[nd][16+tl] + smGh[nd][16+tl])));
            float n = tanhf(smGi[nd][32+tl] + r * smGh[nd][32+tl]);
            float hn = (1.f - z)*n + z*smGin[nd][tl];
            smH[nd][tl] = hn;
        }
        __syncthreads();

        if (!last) {
            if (tl < 128) {
                int o = tl & 63, sel = tl >> 6;
                const floatx4* Wv = (const floatx4*)(sel ? &smW1hj[0][0] : &smW1hi[0][0]);
                floatx4 w0 = Wv[o*4], w1 = Wv[o*4+1], w2 = Wv[o*4+2], w3 = Wv[o*4+3];
                float s = 0.f;
                #pragma unroll
                for (int e = 0; e < 4; ++e) {
                    s = fmaf(w0[e], smH[nd][e],      s);
                    s = fmaf(w1[e], smH[nd][4 + e],  s);
                    s = fmaf(w2[e], smH[nd][8 + e],  s);
                    s = fmaf(w3[e], smH[nd][12 + e], s);
                }
                if (sel == 0) aOut[j*64 + o] = s + smAbias[nd][o];
                else          smC[nd][o] = s + smCbias[nd][o];
            }
            fast_grid_barrier(arrive, go, t + 2, bid, tid);  // a-panel exchange
            float* tmp = aIn; aIn = aOut; aOut = tmp;
        } else {
            if (tl < 64) {
                const floatx4* Wv = (const floatx4*)Wr1;
                floatx4 w0 = Wv[tl*4], w1 = Wv[tl*4+1], w2 = Wv[tl*4+2], w3 = Wv[tl*4+3];
                float s = br1[tl];
                #pragma unroll
                for (int e = 0; e < 4; ++e) {
                    s = fmaf(w0[e], smH[nd][e],      s);
                    s = fmaf(w1[e], smH[nd][4 + e],  s);
                    s = fmaf(w2[e], smH[nd][8 + e],  s);
                    s = fmaf(w3[e], smH[nd][12 + e], s);
                }
                smY[nd][tl] = fmaxf(s, 0.f);
            }
            __syncthreads();
            {   // y2: 64 outputs x 64 inputs, 4 threads per output
                int o = tl >> 2, p = tl & 3;
                const floatx4* Wv = (const floatx4*)Wr2;
                floatx4 w0 = Wv[o*16 + p*4],     w1 = Wv[o*16 + p*4 + 1];
                floatx4 w2 = Wv[o*16 + p*4 + 2], w3 = Wv[o*16 + p*4 + 3];
                int k0 = p*16;
                float part = 0.f;
                #pragma unroll
                for (int e = 0; e < 4; ++e) {
                    part = fmaf(w0[e], smY[nd][k0 + e],      part);
                    part = fmaf(w1[e], smY[nd][k0 + 4 + e],  part);
                    part = fmaf(w2[e], smY[nd][k0 + 8 + e],  part);
                    part = fmaf(w3[e], smY[nd][k0 + 12 + e], part);
                }
                part += __shfl_xor(part, 1);
                part += __shfl_xor(part, 2);
                __syncthreads();
                if (p == 0) smY[nd][o] = fmaxf(part + br2[o], 0.f);
            }
            __syncthreads();
            if (tl < 128) {
                int ot = tl >> 6, p = tl & 63;
                float part = Wr3[ot*64 + p] * smY[nd][p];
                part += __shfl_xor(part, 1);
                part += __shfl_xor(part, 2);
                part += __shfl_xor(part, 4);
                part += __shfl_xor(part, 8);
                part += __shfl_xor(part, 16);
                part += __shfl_xor(part, 32);
                if (p == 0) smR[nd][ot] = part + br3[ot];
            }
            __syncthreads();
            if (tl == 0) {
                float e0 = 1.f/(1.f + __expf(-smR[nd][0]));
                float e1 = 1.f/(1.f + __expf(-smR[nd][1]));
                float tsum = e0 + e1;
                out[j*2]     = e0/tsum;
                out[j*2 + 1] = e1/tsum;
            }
        }
    }
}

// ============================================================================
// Fallback path: the proven multi-launch kernels (verbatim from baseline).
// ============================================================================
__global__ void init_kernel(const float* __restrict__ J, const float* __restrict__ b,
                            const float* __restrict__ W1, const float* __restrict__ b1,
                            const float* __restrict__ W2,
                            float* __restrict__ Jt, float* __restrict__ aG, float* __restrict__ cG,
                            float* __restrict__ h0, float* __restrict__ wJ,
                            float* __restrict__ wbi, float* __restrict__ wbj,
                            float* __restrict__ W1hiT, float* __restrict__ W1hjT,
                            unsigned short* __restrict__ W2bf)
{
    int bx = blockIdx.x, tid = threadIdx.x;
    if (bx < 64) {
        __shared__ float tile[64][65];
        int ti = bx >> 3, tj = bx & 7;
        for (int p = 0; p < 16; ++p) {
            int e = p*256 + tid; int r = e >> 6, c = e & 63;
            tile[r][c] = J[(ti*64 + r)*512 + tj*64 + c];
        }
        __syncthreads();
        for (int p = 0; p < 16; ++p) {
            int e = p*256 + tid; int r = e >> 6, c = e & 63;
            Jt[(tj*64 + r)*512 + ti*64 + c] = tile[c][r];
        }
    } else if (bx < 96) {
        int gid = (bx - 64)*256 + tid;
        for (int p = 0; p < 4; ++p) {
            int idx = p*8192 + gid;
            int i = idx >> 6, o = idx & 63;
            aG[idx] = b[i] * W1[o*35 + 33];
        }
    } else if (bx < 128) {
        int gid = (bx - 96)*256 + tid;
        for (int p = 0; p < 4; ++p) {
            int idx = p*8192 + gid;
            int i = idx >> 6, o = idx & 63;
            cG[idx] = b[i] * W1[o*35 + 34] + b1[o];
        }
    } else if (bx == 128) {
        for (int p = 0; p < 16; ++p) {
            int flat = p*256 + tid;
            int jj = flat & 7;
            int lane = (flat >> 3) & 63;
            int tk = flat >> 9;
            int nt = tk >> 1, ks = tk & 1;
            int n = nt*16 + (lane & 15);
            int k = ks*32 + (lane >> 4)*8 + jj;
            W2bf[flat] = f2bf(W2[n*64 + k]);
        }
        if (tid < 64) {
            wJ[tid]  = W1[tid*35 + 32];
            wbi[tid] = W1[tid*35 + 33];
            wbj[tid] = W1[tid*35 + 34];
            #pragma unroll
            for (int s = 0; s < 16; ++s) {
                W1hiT[tid*16 + s] = W1[tid*35 + s];
                W1hjT[tid*16 + s] = W1[tid*35 + 16 + s];
            }
        }
    } else {
        for (int p = 0; p < 32; ++p) h0[p*256 + tid] = 0.f;
    }
}

__global__ __launch_bounds__(256) void edge_kernel(
    const float* __restrict__ Jt,
    const float* __restrict__ aIn, const float* __restrict__ cIn, const float* __restrict__ hIn,
    float* __restrict__ aOut, float* __restrict__ cOut, float* __restrict__ hOut,
    const unsigned short* __restrict__ W2bf, const float* __restrict__ wJ,
    const float* __restrict__ b2, const float* __restrict__ W3, const float* __restrict__ b3,
    const float* __restrict__ W_ih, const float* __restrict__ b_ih,
    const float* __restrict__ W_hh, const float* __restrict__ b_hh,
    const float* __restrict__ W1hiT, const float* __restrict__ W1hjT,
    const float* __restrict__ wbi, const float* __restrict__ wbj,
    const float* __restrict__ bvec, const float* __restrict__ b1,
    const float* __restrict__ Wr1, const float* __restrict__ br1,
    const float* __restrict__ Wr2, const float* __restrict__ br2,
    const float* __restrict__ Wr3, const float* __restrict__ br3,
    float* __restrict__ out, int last)
{
    const int j = blockIdx.x;
    const int tid = threadIdx.x;
    const int l = tid & 63, w = tid >> 6;
    const int m = l & 15, q = l >> 4;

    __shared__ float smWave[4][64];
    __shared__ float smMacc[64];
    __shared__ float smGin[48];
    __shared__ float smGi[48], smGh[48];
    __shared__ float smH[16];
    __shared__ float smY[64];
    __shared__ float smR[2];

    const floatx4* c4 = (const floatx4*)cIn;
    const floatx4* w4 = (const floatx4*)wJ;
    floatx4 cva = c4[j*16 + q*2],     cvb = c4[j*16 + q*2 + 1];
    floatx4 cvc = c4[j*16 + 8 + q*2], cvd = c4[j*16 + 8 + q*2 + 1];
    floatx4 wva = w4[q*2], wvb = w4[q*2+1], wvc = w4[8+q*2], wvd = w4[8+q*2+1];

    short8 bfw[4][2];
    {
        const short8* wb = (const short8*)W2bf;
        #pragma unroll
        for (int nt = 0; nt < 4; ++nt)
            #pragma unroll
            for (int ks = 0; ks < 2; ++ks)
                bfw[nt][ks] = wb[(nt*2 + ks)*64 + l];
    }
    float b2n[4];
    #pragma unroll
    for (int nt = 0; nt < 4; ++nt) b2n[nt] = b2[nt*16 + m];

    floatx4 acc[4];
    #pragma unroll
    for (int nt = 0; nt < 4; ++nt) acc[nt] = (floatx4){0.f,0.f,0.f,0.f};

    const floatx4* a4 = (const floatx4*)aIn;

    for (int c8 = 0; c8 < 8; ++c8) {
        int i = w*128 + c8*16 + m;
        float Jij = Jt[j*512 + i];
        floatx4 av0 = a4[i*16 + q*2],     av1 = a4[i*16 + q*2 + 1];
        floatx4 av2 = a4[i*16 + 8 + q*2], av3 = a4[i*16 + 8 + q*2 + 1];
        floatx4 x0, x1, x2, x3;
        #pragma unroll
        for (int e = 0; e < 4; ++e) {
            x0[e] = fmaxf(fmaf(Jij, wva[e], av0[e]) + cva[e], 0.f);
            x1[e] = fmaxf(fmaf(Jij, wvb[e], av1[e]) + cvb[e], 0.f);
            x2[e] = fmaxf(fmaf(Jij, wvc[e], av2[e]) + cvc[e], 0.f);
            x3[e] = fmaxf(fmaf(Jij, wvd[e], av3[e]) + cvd[e], 0.f);
        }
        union { short8 s; unsigned u[4]; } fa0, fa1;
        fa0.u[0] = pk2bf(x0[0], x0[1]); fa0.u[1] = pk2bf(x0[2], x0[3]);
        fa0.u[2] = pk2bf(x1[0], x1[1]); fa0.u[3] = pk2bf(x1[2], x1[3]);
        fa1.u[0] = pk2bf(x2[0], x2[1]); fa1.u[1] = pk2bf(x2[2], x2[3]);
        fa1.u[2] = pk2bf(x3[0], x3[1]); fa1.u[3] = pk2bf(x3[2], x3[3]);
        #pragma unroll
        for (int nt = 0; nt < 4; ++nt) {
            floatx4 d = {0.f,0.f,0.f,0.f};
            d = __builtin_amdgcn_mfma_f32_16x16x32_bf16(fa0.s, bfw[nt][0], d, 0, 0, 0);
            d = __builtin_amdgcn_mfma_f32_16x16x32_bf16(fa1.s, bfw[nt][1], d, 0, 0, 0);
            #pragma unroll
            for (int r = 0; r < 4; ++r)
                acc[nt][r] += fmaxf(d[r] + b2n[nt], 0.f);
        }
    }

    #pragma unroll
    for (int nt = 0; nt < 4; ++nt) {
        float v = acc[nt][0] + acc[nt][1] + acc[nt][2] + acc[nt][3];
        v += __shfl_xor(v, 16);
        v += __shfl_xor(v, 32);
        if (l < 16) smWave[w][nt*16 + l] = v;
    }
    if (tid < 16) smGin[tid] = hIn[j*16 + tid];
    __syncthreads();
    if (tid < 64) smMacc[tid] = smWave[0][tid] + smWave[1][tid] + smWave[2][tid] + smWave[3][tid];
    __syncthreads();

    {
        int o = tid >> 3, p = tid & 7;
        const floatx4* W3v = (const floatx4*)W3;
        floatx4 wv0 = W3v[o*16 + p*2], wv1 = W3v[o*16 + p*2 + 1];
        float part = 0.f;
        #pragma unroll
        for (int e = 0; e < 4; ++e) {
            part = fmaf(wv0[e], smMacc[p*8 + e], part);
            part = fmaf(wv1[e], smMacc[p*8 + 4 + e], part);
        }
        part += __shfl_xor(part, 1);
        part += __shfl_xor(part, 2);
        part += __shfl_xor(part, 4);
        if (p == 0) smGin[16 + o] = part + 512.f * b3[o];
    }
    __syncthreads();

    if (tid < 192) {
        int o = tid >> 2, p = tid & 3;
        const floatx4* Wv = (const floatx4*)W_ih;
        floatx4 w0 = Wv[o*12 + p*3], w1 = Wv[o*12 + p*3 + 1], w2 = Wv[o*12 + p*3 + 2];
        int k0 = p*12;
        float part = 0.f;
        #pragma unroll
        for (int e = 0; e < 4; ++e) {
            part = fmaf(w0[e], smGin[k0 + e], part);
            part = fmaf(w1[e], smGin[k0 + 4 + e], part);
            part = fmaf(w2[e], smGin[k0 + 8 + e], part);
        }
        part += __shfl_xor(part, 1);
        part += __shfl_xor(part, 2);
        if (p == 0) smGi[o] = part + b_ih[o];
    } else if (tid < 240) {
        int o = tid - 192;
        const floatx4* Wv = (const floatx4*)W_hh;
        floatx4 w0 = Wv[o*4], w1 = Wv[o*4+1], w2 = Wv[o*4+2], w3 = Wv[o*4+3];
        float s = b_hh[o];
        #pragma unroll
        for (int e = 0; e < 4; ++e) {
            s = fmaf(w0[e], smGin[e],      s);
            s = fmaf(w1[e], smGin[4 + e],  s);
            s = fmaf(w2[e], smGin[8 + e],  s);
            s = fmaf(w3[e], smGin[12 + e], s);
        }
        smGh[o] = s;
    }
    __syncthreads();

    if (tid < 16) {
        float r = 1.f / (1.f + __expf(-(smGi[tid] + smGh[tid])));
        float z = 1.f / (1.f + __expf(-(smGi[16+tid] + smGh[16+tid])));
        float n = tanhf(smGi[32+tid] + r * smGh[32+tid]);
        float hn = (1.f - z)*n + z*smGin[tid];
        hOut[j*16 + tid] = hn;
        smH[tid] = hn;
    }
    __syncthreads();

    if (!last) {
        if (tid < 128) {
            int o = tid & 63, sel = tid >> 6;
            const floatx4* Wv = (const floatx4*)(sel ? W1hjT : W1hiT);
            floatx4 w0 = Wv[o*4], w1 = Wv[o*4+1], w2 = Wv[o*4+2], w3 = Wv[o*4+3];
            float s = 0.f;
            #pragma unroll
            for (int e = 0; e < 4; ++e) {
                s = fmaf(w0[e], smH[e],      s);
                s = fmaf(w1[e], smH[4 + e],  s);
                s = fmaf(w2[e], smH[8 + e],  s);
                s = fmaf(w3[e], smH[12 + e], s);
            }
            if (sel == 0) aOut[j*64 + o] = s + bvec[j]*wbi[o];
            else          cOut[j*64 + o] = s + bvec[j]*wbj[o] + b1[o];
        }
    } else {
        if (tid < 64) {
            const floatx4* Wv = (const floatx4*)Wr1;
            floatx4 w0 = Wv[tid*4], w1 = Wv[tid*4+1], w2 = Wv[tid*4+2], w3 = Wv[tid*4+3];
            float s = br1[tid];
            #pragma unroll
            for (int e = 0; e < 4; ++e) {
                s = fmaf(w0[e], smH[e],      s);
                s = fmaf(w1[e], smH[4 + e],  s);
                s = fmaf(w2[e], smH[8 + e],  s);
                s = fmaf(w3[e], smH[12 + e], s);
            }
            smY[tid] = fmaxf(s, 0.f);
        }
        __syncthreads();
        {
            int o = tid >> 2, p = tid & 3;
            const floatx4* Wv = (const floatx4*)Wr2;
            floatx4 w0 = Wv[o*16 + p*4],     w1 = Wv[o*16 + p*4 + 1];
            floatx4 w2 = Wv[o*16 + p*4 + 2], w3 = Wv[o*16 + p*4 + 3];
            int k0 = p*16;
            float part = 0.f;
            #pragma unroll
            for (int e = 0; e < 4; ++e) {
                part = fmaf(w0[e], smY[k0 + e],      part);
                part = fmaf(w1[e], smY[k0 + 4 + e],  part);
                part = fmaf(w2[e], smY[k0 + 8 + e],  part);
                part = fmaf(w3[e], smY[k0 + 12 + e], part);
            }
            part += __shfl_xor(part, 1);
            part += __shfl_xor(part, 2);
            __syncthreads();
            if (p == 0) smY[o] = fmaxf(part + br2[o], 0.f);
        }
        __syncthreads();
        if (tid < 128) {
            int ot = tid >> 6, p = tid & 63;
            float part = Wr3[ot*64 + p] * smY[p];
            part += __shfl_xor(part, 1);
            part += __shfl_xor(part, 2);
            part += __shfl_xor(part, 4);
            part += __shfl_xor(part, 8);
            part += __shfl_xor(part, 16);
            part += __shfl_xor(part, 32);
            if (p == 0) smR[ot] = part + br3[ot];
        }
        __syncthreads();
        if (tid == 0) {
            float e0 = 1.f/(1.f + __expf(-smR[0]));
            float e1 = 1.f/(1.f + __expf(-smR[1]));
            float t = e0 + e1;
            out[j*2]     = e0/t;
            out[j*2 + 1] = e1/t;
        }
    }
}

extern "C" void kernel_launch(void* const* d_in, const int* in_sizes, int n_in,
                              void* d_out, int out_size, void* d_ws, size_t ws_size,
                              hipStream_t stream)
{
    const float* J    = (const float*)d_in[0];
    const float* b    = (const float*)d_in[1];
    const float* W1   = (const float*)d_in[2];
    const float* b1   = (const float*)d_in[3];
    const float* W2   = (const float*)d_in[4];
    const float* b2   = (const float*)d_in[5];
    const float* W3   = (const float*)d_in[6];
    const float* b3   = (const float*)d_in[7];
    const float* W_ih = (const float*)d_in[8];
    const float* b_ih = (const float*)d_in[9];
    const float* W_hh = (const float*)d_in[10];
    const float* b_hh = (const float*)d_in[11];
    const float* Wr1  = (const float*)d_in[12];
    const float* br1  = (const float*)d_in[13];
    const float* Wr2  = (const float*)d_in[14];
    const float* br2  = (const float*)d_in[15];
    const float* Wr3  = (const float*)d_in[16];
    const float* br3  = (const float*)d_in[17];
    float* outp = (float*)d_out;

    float* ws = (float*)d_ws;

    static int coop_attr = -1;
    if (coop_attr < 0) {
        int v = 0;
        if (hipDeviceGetAttribute(&v, hipDeviceAttributeCooperativeLaunch, 0) != hipSuccess) v = 0;
        coop_attr = v;
    }

    float* aBuf0 = ws;
    float* aBuf1 = ws + 32768;
    int*   flags = (int*)(ws + 65536);           // 2 * 256 * 32 ints = 64 KB
    const size_t FLAG_BYTES = 2u * 256u * FLAG_STRIDE * sizeof(int);

    hipError_t lerr = hipErrorUnknown;
    if (coop_attr) {
        // zero the barrier flags (epochs start at 1)
        hipError_t merr = hipMemsetAsync((void*)flags, 0, FLAG_BYTES, stream);
        if (merr == hipSuccess) {
            void* args[] = {
                (void*)&J, (void*)&b, (void*)&W1, (void*)&b1, (void*)&W2, (void*)&b2,
                (void*)&W3, (void*)&b3, (void*)&W_ih, (void*)&b_ih, (void*)&W_hh, (void*)&b_hh,
                (void*)&Wr1, (void*)&br1, (void*)&Wr2, (void*)&br2, (void*)&Wr3, (void*)&br3,
                (void*)&aBuf0, (void*)&aBuf1, (void*)&flags, (void*)&outp
            };
            lerr = hipLaunchCooperativeKernel(reinterpret_cast<void*>(fused2_kernel),
                                              dim3(NN/2), dim3(512), args, 0, stream);
        }
    }
    if (lerr == hipSuccess) return;
    (void)hipGetLastError();   // clear error state before fallback

    // --- fallback: proven multi-launch path ---
    float* Jt   = ws + 131072;
    float* aG0  = Jt + 262144;
    float* aG1  = aG0 + 32768;
    float* cG0  = aG1 + 32768;
    float* cG1  = cG0 + 32768;
    float* hA   = cG1 + 32768;
    float* hB   = hA + 8192;
    float* wJ   = hB + 8192;
    float* wbi  = wJ + 64;
    float* wbj  = wbi + 64;
    float* W1hiT = wbj + 64;
    float* W1hjT = W1hiT + 1024;
    unsigned short* W2bf = (unsigned short*)(W1hjT + 1024);

    hipLaunchKernelGGL(init_kernel, dim3(130), dim3(256), 0, stream,
                       J, b, W1, b1, W2, Jt, aG0, cG0, hA, wJ, wbi, wbj, W1hiT, W1hjT, W2bf);

    float* aIn = aG0; float* aOut = aG1;
    float* cIn = cG0; float* cOut = cG1;
    float* hI  = hA;  float* hO  = hB;
    for (int t = 0; t < NSTEPS; ++t) {
        hipLaunchKernelGGL(edge_kernel, dim3(512), dim3(256), 0, stream,
            Jt, aIn, cIn, hI, aOut, cOut, hO, W2bf, wJ, b2, W3, b3,
            W_ih, b_ih, W_hh, b_hh, W1hiT, W1hjT, wbi, wbj, b, b1,
            Wr1, br1, Wr2, br2, Wr3, br3, outp, (t == NSTEPS-1) ? 1 : 0);
        float* tmp;
        tmp = aIn; aIn = aOut; aOut = tmp;
        tmp = cIn; cIn = cOut; cOut = tmp;
        tmp = hI;  hI  = hO;  hO  = tmp;
    }
}

// Round 4
// 211.381 us; speedup vs baseline: 2.2458x; 2.2458x over previous
//
#include <hip/hip_runtime.h>
#include <hip/hip_bf16.h>

#define NN 512
#define NSTEPS 5
#define FSTR 32   // flag stride in ints: 128 B/flag, one line each

typedef __attribute__((ext_vector_type(8))) short short8;
typedef __attribute__((ext_vector_type(4))) float floatx4;

static __device__ __forceinline__ unsigned short f2bf(float f) {
    union { float f; unsigned u; } x; x.f = f;
    unsigned r = x.u + 0x7fffu + ((x.u >> 16) & 1u);
    return (unsigned short)(r >> 16);
}

static __device__ __forceinline__ unsigned pk2bf(float a, float b) {
    __hip_bfloat162 h = __float22bfloat162_rn(make_float2(a, b));
    return *reinterpret_cast<unsigned*>(&h);
}

// ============================================================================
// Barrier-free fused kernel: 256 blocks x 512 threads, 2 nodes per block.
// Cross-block exchange via per-node ready flags + 5 distinct panel buffers:
//   producer: agent-scope (L2-bypassing) stores of its 64-float row -> IF$,
//             vmcnt(0), then relaxed agent flag store flag[j] = s.
//   consumer: spins on flags of the 8 rows it reads (usually already set),
//             then PLAIN CACHED vector loads (buffer s is never written after
//             its flags are set, and never read before -> no stale L2 lines).
// Safety of buffer reuse is moot: one buffer per step (a^1..a^5).
// Skew bound: producing a^{s+1} requires consuming all of a^s, which requires
// all of a^s produced, which requires every block done reading a^{s-1}.
// ============================================================================
__global__ __launch_bounds__(512, 2) void fused3_kernel(
    const float* __restrict__ J, const float* __restrict__ b,
    const float* __restrict__ W1, const float* __restrict__ b1,
    const float* __restrict__ W2, const float* __restrict__ b2,
    const float* __restrict__ W3, const float* __restrict__ b3,
    const float* __restrict__ W_ih, const float* __restrict__ b_ih,
    const float* __restrict__ W_hh, const float* __restrict__ b_hh,
    const float* __restrict__ Wr1, const float* __restrict__ br1,
    const float* __restrict__ Wr2, const float* __restrict__ br2,
    const float* __restrict__ Wr3, const float* __restrict__ br3,
    float* __restrict__ aP, int* __restrict__ flag,
    float* __restrict__ out)
{
    const int tid = threadIdx.x;
    const int bid = blockIdx.x;
    const int nd = tid >> 8;          // which of the block's 2 nodes
    const int tl = tid & 255;         // local tid within node group
    const int j  = bid * 2 + nd;
    const int l  = tid & 63, w4 = tl >> 6;
    const int m  = l & 15,  q  = l >> 4;

    __shared__ float smW1hi[64][16], smW1hj[64][16];
    __shared__ float smC[2][64], smAbias[2][64], smCbias[2][64];
    __shared__ float smWave[2][4][64], smMacc[2][64];
    __shared__ float smGin[2][48], smGi[2][48], smGh[2][48];
    __shared__ float smH[2][16], smY[2][64], smR[2][2];

    // Drop stale clean L1/L2 lines of the workspace (harness poison-fill and
    // previous graph replays leave clean copies). After this, panel lines can
    // only enter this XCD's L2 via flag-gated reads -> always fresh from IF$.
    __builtin_amdgcn_fence(__ATOMIC_ACQUIRE, "agent");

    // ---- publish a^1 (bias-only, h0=0) + per-node meta ----
    if (tid < 128) {
        int nd0 = tid >> 6, o = tid & 63;
        int j0 = bid*2 + nd0;
        float bj0 = b[j0];
        const float* w1r = W1 + o*35;
        float ab = bj0 * w1r[33];
        smAbias[nd0][o] = ab;
        float cb = bj0 * w1r[34] + b1[o];
        smCbias[nd0][o] = cb;
        smC[nd0][o] = cb;                  // h0 = 0 -> c0 bias-only
        __hip_atomic_store(&aP[32768 + j0*64 + o], ab,
                           __ATOMIC_RELAXED, __HIP_MEMORY_SCOPE_AGENT);
    }
    if (tid < 128) {   // waves 0,1 whole: wave-uniform
        asm volatile("s_waitcnt vmcnt(0)" ::: "memory");
        if ((tid & 63) == 0)
            __hip_atomic_store(&flag[(bid*2 + (tid >> 6))*FSTR], 1,
                               __ATOMIC_RELAXED, __HIP_MEMORY_SCOPE_AGENT);
    }
    if (tid >= 128 && tid < 160) {
        int nd0 = (tid - 128) >> 4, o = (tid - 128) & 15;
        smH[nd0][o] = 0.f;
    }
    if (tid < 64) {
        const float* w1r = W1 + tid*35;
        #pragma unroll
        for (int s0 = 0; s0 < 16; ++s0) {
            smW1hi[tid][s0] = w1r[s0];
            smW1hj[tid][s0] = w1r[16 + s0];
        }
    }

    // J column for this node (i = w4*128 + c8*16 + m), once
    float Jr[8];
    #pragma unroll
    for (int c8 = 0; c8 < 8; ++c8)
        Jr[c8] = J[(w4*128 + c8*16 + m)*512 + j];

    // wJ vectors for this lane's o-set
    floatx4 wva, wvb, wvc, wvd;
    #pragma unroll
    for (int e = 0; e < 4; ++e) {
        wva[e] = W1[(q*8 + e)*35 + 32];
        wvb[e] = W1[(q*8 + 4 + e)*35 + 32];
        wvc[e] = W1[(32 + q*8 + e)*35 + 32];
        wvd[e] = W1[(32 + q*8 + 4 + e)*35 + 32];
    }

    // W2 B-fragments, in-register, once. B[k][n] = W2[n][k]
    short8 bfw[4][2];
    #pragma unroll
    for (int nt = 0; nt < 4; ++nt) {
        #pragma unroll
        for (int ks = 0; ks < 2; ++ks) {
            union { short8 s; unsigned short us[8]; } tpk;
            int n = nt*16 + m;
            #pragma unroll
            for (int jj = 0; jj < 8; ++jj)
                tpk.us[jj] = f2bf(W2[n*64 + ks*32 + q*8 + jj]);
            bfw[nt][ks] = tpk.s;
        }
    }
    float b2n[4];
    #pragma unroll
    for (int nt = 0; nt < 4; ++nt) b2n[nt] = b2[nt*16 + m];

    __syncthreads();   // smC / smW1 / smH ready

    for (int t = 0; t < NSTEPS; ++t) {
        const int last = (t == NSTEPS - 1);
        const int s = t + 1;               // panel generation consumed now

        floatx4 cva, cvb, cvc, cvd;
        #pragma unroll
        for (int e = 0; e < 4; ++e) {
            cva[e] = smC[nd][q*8 + e];
            cvb[e] = smC[nd][q*8 + 4 + e];
            cvc[e] = smC[nd][32 + q*8 + e];
            cvd[e] = smC[nd][32 + q*8 + 4 + e];
        }

        // wait for the 8 rows this lane reads
        #pragma unroll
        for (int c8 = 0; c8 < 8; ++c8) {
            int i = w4*128 + c8*16 + m;
            while (__hip_atomic_load(&flag[i*FSTR], __ATOMIC_RELAXED,
                                     __HIP_MEMORY_SCOPE_AGENT) < s)
                __builtin_amdgcn_s_sleep(1);
        }
        asm volatile("" ::: "memory");     // no hoisting panel loads above spins

        floatx4 acc[4];
        #pragma unroll
        for (int nt = 0; nt < 4; ++nt) acc[nt] = (floatx4){0.f,0.f,0.f,0.f};

        const floatx4* a4 = (const floatx4*)(aP + (size_t)s*32768);

        for (int c8 = 0; c8 < 8; ++c8) {
            int i = w4*128 + c8*16 + m;
            float Jij = Jr[c8];
            floatx4 av0 = a4[i*16 + q*2],     av1 = a4[i*16 + q*2 + 1];
            floatx4 av2 = a4[i*16 + 8 + q*2], av3 = a4[i*16 + 8 + q*2 + 1];
            floatx4 x0, x1, x2, x3;
            #pragma unroll
            for (int e = 0; e < 4; ++e) {
                x0[e] = fmaxf(fmaf(Jij, wva[e], av0[e]) + cva[e], 0.f);
                x1[e] = fmaxf(fmaf(Jij, wvb[e], av1[e]) + cvb[e], 0.f);
                x2[e] = fmaxf(fmaf(Jij, wvc[e], av2[e]) + cvc[e], 0.f);
                x3[e] = fmaxf(fmaf(Jij, wvd[e], av3[e]) + cvd[e], 0.f);
            }
            union { short8 s; unsigned u[4]; } fa0, fa1;
            fa0.u[0] = pk2bf(x0[0], x0[1]); fa0.u[1] = pk2bf(x0[2], x0[3]);
            fa0.u[2] = pk2bf(x1[0], x1[1]); fa0.u[3] = pk2bf(x1[2], x1[3]);
            fa1.u[0] = pk2bf(x2[0], x2[1]); fa1.u[1] = pk2bf(x2[2], x2[3]);
            fa1.u[2] = pk2bf(x3[0], x3[1]); fa1.u[3] = pk2bf(x3[2], x3[3]);
            #pragma unroll
            for (int nt = 0; nt < 4; ++nt) {
                floatx4 d = {0.f,0.f,0.f,0.f};
                d = __builtin_amdgcn_mfma_f32_16x16x32_bf16(fa0.s, bfw[nt][0], d, 0, 0, 0);
                d = __builtin_amdgcn_mfma_f32_16x16x32_bf16(fa1.s, bfw[nt][1], d, 0, 0, 0);
                #pragma unroll
                for (int r = 0; r < 4; ++r)
                    acc[nt][r] += fmaxf(d[r] + b2n[nt], 0.f);
            }
        }

        // reduce rows within wave, stage h into smGin
        #pragma unroll
        for (int nt = 0; nt < 4; ++nt) {
            float v = acc[nt][0] + acc[nt][1] + acc[nt][2] + acc[nt][3];
            v += __shfl_xor(v, 16);
            v += __shfl_xor(v, 32);
            if (l < 16) smWave[nd][w4][nt*16 + l] = v;
        }
        if (tl < 16) smGin[nd][tl] = smH[nd][tl];
        __syncthreads();
        if (tl < 64) smMacc[nd][tl] = smWave[nd][0][tl] + smWave[nd][1][tl]
                                    + smWave[nd][2][tl] + smWave[nd][3][tl];
        __syncthreads();

        // msg = W3 @ macc + 512*b3
        {
            int o = tl >> 3, p = tl & 7;
            const floatx4* W3v = (const floatx4*)W3;
            floatx4 wv0 = W3v[o*16 + p*2], wv1 = W3v[o*16 + p*2 + 1];
            float part = 0.f;
            #pragma unroll
            for (int e = 0; e < 4; ++e) {
                part = fmaf(wv0[e], smMacc[nd][p*8 + e], part);
                part = fmaf(wv1[e], smMacc[nd][p*8 + 4 + e], part);
            }
            part += __shfl_xor(part, 1);
            part += __shfl_xor(part, 2);
            part += __shfl_xor(part, 4);
            if (p == 0) smGin[nd][16 + o] = part + 512.f * b3[o];
        }
        __syncthreads();

        // GRU gates
        if (tl < 192) {
            int o = tl >> 2, p = tl & 3;
            const floatx4* Wv = (const floatx4*)W_ih;
            floatx4 w0 = Wv[o*12 + p*3], w1 = Wv[o*12 + p*3 + 1], w2 = Wv[o*12 + p*3 + 2];
            int k0 = p*12;
            float part = 0.f;
            #pragma unroll
            for (int e = 0; e < 4; ++e) {
                part = fmaf(w0[e], smGin[nd][k0 + e], part);
                part = fmaf(w1[e], smGin[nd][k0 + 4 + e], part);
                part = fmaf(w2[e], smGin[nd][k0 + 8 + e], part);
            }
            part += __shfl_xor(part, 1);
            part += __shfl_xor(part, 2);
            if (p == 0) smGi[nd][o] = part + b_ih[o];
        } else if (tl < 240) {
            int o = tl - 192;
            const floatx4* Wv = (const floatx4*)W_hh;
            floatx4 w0 = Wv[o*4], w1 = Wv[o*4+1], w2 = Wv[o*4+2], w3 = Wv[o*4+3];
            float s2 = b_hh[o];
            #pragma unroll
            for (int e = 0; e < 4; ++e) {
                s2 = fmaf(w0[e], smGin[nd][e],      s2);
                s2 = fmaf(w1[e], smGin[nd][4 + e],  s2);
                s2 = fmaf(w2[e], smGin[nd][8 + e],  s2);
                s2 = fmaf(w3[e], smGin[nd][12 + e], s2);
            }
            smGh[nd][o] = s2;
        }
        __syncthreads();

        if (tl < 16) {
            float r = 1.f / (1.f + __expf(-(smGi[nd][tl] + smGh[nd][tl])));
            float z = 1.f / (1.f + __expf(-(smGi[nd][16+tl] + smGh[nd][16+tl])));
            float n = tanhf(smGi[nd][32+tl] + r * smGh[nd][32+tl]);
            float hn = (1.f - z)*n + z*smGin[nd][tl];
            smH[nd][tl] = hn;
        }
        __syncthreads();

        if (!last) {
            if (tl < 128) {
                int o = tl & 63, sel = tl >> 6;
                const floatx4* Wv = (const floatx4*)(sel ? &smW1hj[0][0] : &smW1hi[0][0]);
                floatx4 w0 = Wv[o*4], w1 = Wv[o*4+1], w2 = Wv[o*4+2], w3 = Wv[o*4+3];
                float sacc = 0.f;
                #pragma unroll
                for (int e = 0; e < 4; ++e) {
                    sacc = fmaf(w0[e], smH[nd][e],      sacc);
                    sacc = fmaf(w1[e], smH[nd][4 + e],  sacc);
                    sacc = fmaf(w2[e], smH[nd][8 + e],  sacc);
                    sacc = fmaf(w3[e], smH[nd][12 + e], sacc);
                }
                if (sel == 0) {
                    // publish next panel row straight to the coherent point
                    __hip_atomic_store(&aP[(size_t)(s+1)*32768 + j*64 + o],
                                       sacc + smAbias[nd][o],
                                       __ATOMIC_RELAXED, __HIP_MEMORY_SCOPE_AGENT);
                } else {
                    smC[nd][o] = sacc + smCbias[nd][o];
                }
            }
            if (tl < 64) {   // the producer wave: fence then set flag
                asm volatile("s_waitcnt vmcnt(0)" ::: "memory");
                if (tl == 0)
                    __hip_atomic_store(&flag[j*FSTR], s + 1,
                                       __ATOMIC_RELAXED, __HIP_MEMORY_SCOPE_AGENT);
            }
            __syncthreads();   // protects smC for next iteration's reads
        } else {
            if (tl < 64) {
                const floatx4* Wv = (const floatx4*)Wr1;
                floatx4 w0 = Wv[tl*4], w1 = Wv[tl*4+1], w2 = Wv[tl*4+2], w3 = Wv[tl*4+3];
                float sacc = br1[tl];
                #pragma unroll
                for (int e = 0; e < 4; ++e) {
                    sacc = fmaf(w0[e], smH[nd][e],      sacc);
                    sacc = fmaf(w1[e], smH[nd][4 + e],  sacc);
                    sacc = fmaf(w2[e], smH[nd][8 + e],  sacc);
                    sacc = fmaf(w3[e], smH[nd][12 + e], sacc);
                }
                smY[nd][tl] = fmaxf(sacc, 0.f);
            }
            __syncthreads();
            {   // y2: 64 outputs x 64 inputs, 4 threads per output
                int o = tl >> 2, p = tl & 3;
                const floatx4* Wv = (const floatx4*)Wr2;
                floatx4 w0 = Wv[o*16 + p*4],     w1 = Wv[o*16 + p*4 + 1];
                floatx4 w2 = Wv[o*16 + p*4 + 2], w3 = Wv[o*16 + p*4 + 3];
                int k0 = p*16;
                float part = 0.f;
                #pragma unroll
                for (int e = 0; e < 4; ++e) {
                    part = fmaf(w0[e], smY[nd][k0 + e],      part);
                    part = fmaf(w1[e], smY[nd][k0 + 4 + e],  part);
                    part = fmaf(w2[e], smY[nd][k0 + 8 + e],  part);
                    part = fmaf(w3[e], smY[nd][k0 + 12 + e], part);
                }
                part += __shfl_xor(part, 1);
                part += __shfl_xor(part, 2);
                __syncthreads();
                if (p == 0) smY[nd][o] = fmaxf(part + br2[o], 0.f);
            }
            __syncthreads();
            if (tl < 128) {
                int ot = tl >> 6, p = tl & 63;
                float part = Wr3[ot*64 + p] * smY[nd][p];
                part += __shfl_xor(part, 1);
                part += __shfl_xor(part, 2);
                part += __shfl_xor(part, 4);
                part += __shfl_xor(part, 8);
                part += __shfl_xor(part, 16);
                part += __shfl_xor(part, 32);
                if (p == 0) smR[nd][ot] = part + br3[ot];
            }
            __syncthreads();
            if (tl == 0) {
                float e0 = 1.f/(1.f + __expf(-smR[nd][0]));
                float e1 = 1.f/(1.f + __expf(-smR[nd][1]));
                float tsum = e0 + e1;
                out[j*2]     = e0/tsum;
                out[j*2 + 1] = e1/tsum;
            }
        }
    }
}

// ============================================================================
// Fallback path: the proven multi-launch kernels (verbatim from baseline).
// ============================================================================
__global__ void init_kernel(const float* __restrict__ J, const float* __restrict__ b,
                            const float* __restrict__ W1, const float* __restrict__ b1,
                            const float* __restrict__ W2,
                            float* __restrict__ Jt, float* __restrict__ aG, float* __restrict__ cG,
                            float* __restrict__ h0, float* __restrict__ wJ,
                            float* __restrict__ wbi, float* __restrict__ wbj,
                            float* __restrict__ W1hiT, float* __restrict__ W1hjT,
                            unsigned short* __restrict__ W2bf)
{
    int bx = blockIdx.x, tid = threadIdx.x;
    if (bx < 64) {
        __shared__ float tile[64][65];
        int ti = bx >> 3, tj = bx & 7;
        for (int p = 0; p < 16; ++p) {
            int e = p*256 + tid; int r = e >> 6, c = e & 63;
            tile[r][c] = J[(ti*64 + r)*512 + tj*64 + c];
        }
        __syncthreads();
        for (int p = 0; p < 16; ++p) {
            int e = p*256 + tid; int r = e >> 6, c = e & 63;
            Jt[(tj*64 + r)*512 + ti*64 + c] = tile[c][r];
        }
    } else if (bx < 96) {
        int gid = (bx - 64)*256 + tid;
        for (int p = 0; p < 4; ++p) {
            int idx = p*8192 + gid;
            int i = idx >> 6, o = idx & 63;
            aG[idx] = b[i] * W1[o*35 + 33];
        }
    } else if (bx < 128) {
        int gid = (bx - 96)*256 + tid;
        for (int p = 0; p < 4; ++p) {
            int idx = p*8192 + gid;
            int i = idx >> 6, o = idx & 63;
            cG[idx] = b[i] * W1[o*35 + 34] + b1[o];
        }
    } else if (bx == 128) {
        for (int p = 0; p < 16; ++p) {
            int flat = p*256 + tid;
            int jj = flat & 7;
            int lane = (flat >> 3) & 63;
            int tk = flat >> 9;
            int nt = tk >> 1, ks = tk & 1;
            int n = nt*16 + (lane & 15);
            int k = ks*32 + (lane >> 4)*8 + jj;
            W2bf[flat] = f2bf(W2[n*64 + k]);
        }
        if (tid < 64) {
            wJ[tid]  = W1[tid*35 + 32];
            wbi[tid] = W1[tid*35 + 33];
            wbj[tid] = W1[tid*35 + 34];
            #pragma unroll
            for (int s = 0; s < 16; ++s) {
                W1hiT[tid*16 + s] = W1[tid*35 + s];
                W1hjT[tid*16 + s] = W1[tid*35 + 16 + s];
            }
        }
    } else {
        for (int p = 0; p < 32; ++p) h0[p*256 + tid] = 0.f;
    }
}

__global__ __launch_bounds__(256) void edge_kernel(
    const float* __restrict__ Jt,
    const float* __restrict__ aIn, const float* __restrict__ cIn, const float* __restrict__ hIn,
    float* __restrict__ aOut, float* __restrict__ cOut, float* __restrict__ hOut,
    const unsigned short* __restrict__ W2bf, const float* __restrict__ wJ,
    const float* __restrict__ b2, const float* __restrict__ W3, const float* __restrict__ b3,
    const float* __restrict__ W_ih, const float* __restrict__ b_ih,
    const float* __restrict__ W_hh, const float* __restrict__ b_hh,
    const float* __restrict__ W1hiT, const float* __restrict__ W1hjT,
    const float* __restrict__ wbi, const float* __restrict__ wbj,
    const float* __restrict__ bvec, const float* __restrict__ b1,
    const float* __restrict__ Wr1, const float* __restrict__ br1,
    const float* __restrict__ Wr2, const float* __restrict__ br2,
    const float* __restrict__ Wr3, const float* __restrict__ br3,
    float* __restrict__ out, int last)
{
    const int j = blockIdx.x;
    const int tid = threadIdx.x;
    const int l = tid & 63, w = tid >> 6;
    const int m = l & 15, q = l >> 4;

    __shared__ float smWave[4][64];
    __shared__ float smMacc[64];
    __shared__ float smGin[48];
    __shared__ float smGi[48], smGh[48];
    __shared__ float smH[16];
    __shared__ float smY[64];
    __shared__ float smR[2];

    const floatx4* c4 = (const floatx4*)cIn;
    const floatx4* w4 = (const floatx4*)wJ;
    floatx4 cva = c4[j*16 + q*2],     cvb = c4[j*16 + q*2 + 1];
    floatx4 cvc = c4[j*16 + 8 + q*2], cvd = c4[j*16 + 8 + q*2 + 1];
    floatx4 wva = w4[q*2], wvb = w4[q*2+1], wvc = w4[8+q*2], wvd = w4[8+q*2+1];

    short8 bfw[4][2];
    {
        const short8* wb = (const short8*)W2bf;
        #pragma unroll
        for (int nt = 0; nt < 4; ++nt)
            #pragma unroll
            for (int ks = 0; ks < 2; ++ks)
                bfw[nt][ks] = wb[(nt*2 + ks)*64 + l];
    }
    float b2n[4];
    #pragma unroll
    for (int nt = 0; nt < 4; ++nt) b2n[nt] = b2[nt*16 + m];

    floatx4 acc[4];
    #pragma unroll
    for (int nt = 0; nt < 4; ++nt) acc[nt] = (floatx4){0.f,0.f,0.f,0.f};

    const floatx4* a4 = (const floatx4*)aIn;

    for (int c8 = 0; c8 < 8; ++c8) {
        int i = w*128 + c8*16 + m;
        float Jij = Jt[j*512 + i];
        floatx4 av0 = a4[i*16 + q*2],     av1 = a4[i*16 + q*2 + 1];
        floatx4 av2 = a4[i*16 + 8 + q*2], av3 = a4[i*16 + 8 + q*2 + 1];
        floatx4 x0, x1, x2, x3;
        #pragma unroll
        for (int e = 0; e < 4; ++e) {
            x0[e] = fmaxf(fmaf(Jij, wva[e], av0[e]) + cva[e], 0.f);
            x1[e] = fmaxf(fmaf(Jij, wvb[e], av1[e]) + cvb[e], 0.f);
            x2[e] = fmaxf(fmaf(Jij, wvc[e], av2[e]) + cvc[e], 0.f);
            x3[e] = fmaxf(fmaf(Jij, wvd[e], av3[e]) + cvd[e], 0.f);
        }
        union { short8 s; unsigned u[4]; } fa0, fa1;
        fa0.u[0] = pk2bf(x0[0], x0[1]); fa0.u[1] = pk2bf(x0[2], x0[3]);
        fa0.u[2] = pk2bf(x1[0], x1[1]); fa0.u[3] = pk2bf(x1[2], x1[3]);
        fa1.u[0] = pk2bf(x2[0], x2[1]); fa1.u[1] = pk2bf(x2[2], x2[3]);
        fa1.u[2] = pk2bf(x3[0], x3[1]); fa1.u[3] = pk2bf(x3[2], x3[3]);
        #pragma unroll
        for (int nt = 0; nt < 4; ++nt) {
            floatx4 d = {0.f,0.f,0.f,0.f};
            d = __builtin_amdgcn_mfma_f32_16x16x32_bf16(fa0.s, bfw[nt][0], d, 0, 0, 0);
            d = __builtin_amdgcn_mfma_f32_16x16x32_bf16(fa1.s, bfw[nt][1], d, 0, 0, 0);
            #pragma unroll
            for (int r = 0; r < 4; ++r)
                acc[nt][r] += fmaxf(d[r] + b2n[nt], 0.f);
        }
    }

    #pragma unroll
    for (int nt = 0; nt < 4; ++nt) {
        float v = acc[nt][0] + acc[nt][1] + acc[nt][2] + acc[nt][3];
        v += __shfl_xor(v, 16);
        v += __shfl_xor(v, 32);
        if (l < 16) smWave[w][nt*16 + l] = v;
    }
    if (tid < 16) smGin[tid] = hIn[j*16 + tid];
    __syncthreads();
    if (tid < 64) smMacc[tid] = smWave[0][tid] + smWave[1][tid] + smWave[2][tid] + smWave[3][tid];
    __syncthreads();

    {
        int o = tid >> 3, p = tid & 7;
        const floatx4* W3v = (const floatx4*)W3;
        floatx4 wv0 = W3v[o*16 + p*2], wv1 = W3v[o*16 + p*2 + 1];
        float part = 0.f;
        #pragma unroll
        for (int e = 0; e < 4; ++e) {
            part = fmaf(wv0[e], smMacc[p*8 + e], part);
            part = fmaf(wv1[e], smMacc[p*8 + 4 + e], part);
        }
        part += __shfl_xor(part, 1);
        part += __shfl_xor(part, 2);
        part += __shfl_xor(part, 4);
        if (p == 0) smGin[16 + o] = part + 512.f * b3[o];
    }
    __syncthreads();

    if (tid < 192) {
        int o = tid >> 2, p = tid & 3;
        const floatx4* Wv = (const floatx4*)W_ih;
        floatx4 w0 = Wv[o*12 + p*3], w1 = Wv[o*12 + p*3 + 1], w2 = Wv[o*12 + p*3 + 2];
        int k0 = p*12;
        float part = 0.f;
        #pragma unroll
        for (int e = 0; e < 4; ++e) {
            part = fmaf(w0[e], smGin[k0 + e], part);
            part = fmaf(w1[e], smGin[k0 + 4 + e], part);
            part = fmaf(w2[e], smGin[k0 + 8 + e], part);
        }
        part += __shfl_xor(part, 1);
        part += __shfl_xor(part, 2);
        if (p == 0) smGi[o] = part + b_ih[o];
    } else if (tid < 240) {
        int o = tid - 192;
        const floatx4* Wv = (const floatx4*)W_hh;
        floatx4 w0 = Wv[o*4], w1 = Wv[o*4+1], w2 = Wv[o*4+2], w3 = Wv[o*4+3];
        float s = b_hh[o];
        #pragma unroll
        for (int e = 0; e < 4; ++e) {
            s = fmaf(w0[e], smGin[e],      s);
            s = fmaf(w1[e], smGin[4 + e],  s);
            s = fmaf(w2[e], smGin[8 + e],  s);
            s = fmaf(w3[e], smGin[12 + e], s);
        }
        smGh[o] = s;
    }
    __syncthreads();

    if (tid < 16) {
        float r = 1.f / (1.f + __expf(-(smGi[tid] + smGh[tid])));
        float z = 1.f / (1.f + __expf(-(smGi[16+tid] + smGh[16+tid])));
        float n = tanhf(smGi[32+tid] + r * smGh[32+tid]);
        float hn = (1.f - z)*n + z*smGin[tid];
        hOut[j*16 + tid] = hn;
        smH[tid] = hn;
    }
    __syncthreads();

    if (!last) {
        if (tid < 128) {
            int o = tid & 63, sel = tid >> 6;
            const floatx4* Wv = (const floatx4*)(sel ? W1hjT : W1hiT);
            floatx4 w0 = Wv[o*4], w1 = Wv[o*4+1], w2 = Wv[o*4+2], w3 = Wv[o*4+3];
            float s = 0.f;
            #pragma unroll
            for (int e = 0; e < 4; ++e) {
                s = fmaf(w0[e], smH[e],      s);
                s = fmaf(w1[e], smH[4 + e],  s);
                s = fmaf(w2[e], smH[8 + e],  s);
                s = fmaf(w3[e], smH[12 + e], s);
            }
            if (sel == 0) aOut[j*64 + o] = s + bvec[j]*wbi[o];
            else          cOut[j*64 + o] = s + bvec[j]*wbj[o] + b1[o];
        }
    } else {
        if (tid < 64) {
            const floatx4* Wv = (const floatx4*)Wr1;
            floatx4 w0 = Wv[tid*4], w1 = Wv[tid*4+1], w2 = Wv[tid*4+2], w3 = Wv[tid*4+3];
            float s = br1[tid];
            #pragma unroll
            for (int e = 0; e < 4; ++e) {
                s = fmaf(w0[e], smH[e],      s);
                s = fmaf(w1[e], smH[4 + e],  s);
                s = fmaf(w2[e], smH[8 + e],  s);
                s = fmaf(w3[e], smH[12 + e], s);
            }
            smY[tid] = fmaxf(s, 0.f);
        }
        __syncthreads();
        {
            int o = tid >> 2, p = tid & 3;
            const floatx4* Wv = (const floatx4*)Wr2;
            floatx4 w0 = Wv[o*16 + p*4],     w1 = Wv[o*16 + p*4 + 1];
            floatx4 w2 = Wv[o*16 + p*4 + 2], w3 = Wv[o*16 + p*4 + 3];
            int k0 = p*16;
            float part = 0.f;
            #pragma unroll
            for (int e = 0; e < 4; ++e) {
                part = fmaf(w0[e], smY[k0 + e],      part);
                part = fmaf(w1[e], smY[k0 + 4 + e],  part);
                part = fmaf(w2[e], smY[k0 + 8 + e],  part);
                part = fmaf(w3[e], smY[k0 + 12 + e], part);
            }
            part += __shfl_xor(part, 1);
            part += __shfl_xor(part, 2);
            __syncthreads();
            if (p == 0) smY[o] = fmaxf(part + br2[o], 0.f);
        }
        __syncthreads();
        if (tid < 128) {
            int ot = tid >> 6, p = tid & 63;
            float part = Wr3[ot*64 + p] * smY[p];
            part += __shfl_xor(part, 1);
            part += __shfl_xor(part, 2);
            part += __shfl_xor(part, 4);
            part += __shfl_xor(part, 8);
            part += __shfl_xor(part, 16);
            part += __shfl_xor(part, 32);
            if (p == 0) smR[ot] = part + br3[ot];
        }
        __syncthreads();
        if (tid == 0) {
            float e0 = 1.f/(1.f + __expf(-smR[0]));
            float e1 = 1.f/(1.f + __expf(-smR[1]));
            float t = e0 + e1;
            out[j*2]     = e0/t;
            out[j*2 + 1] = e1/t;
        }
    }
}

extern "C" void kernel_launch(void* const* d_in, const int* in_sizes, int n_in,
                              void* d_out, int out_size, void* d_ws, size_t ws_size,
                              hipStream_t stream)
{
    const float* J    = (const float*)d_in[0];
    const float* b    = (const float*)d_in[1];
    const float* W1   = (const float*)d_in[2];
    const float* b1   = (const float*)d_in[3];
    const float* W2   = (const float*)d_in[4];
    const float* b2   = (const float*)d_in[5];
    const float* W3   = (const float*)d_in[6];
    const float* b3   = (const float*)d_in[7];
    const float* W_ih = (const float*)d_in[8];
    const float* b_ih = (const float*)d_in[9];
    const float* W_hh = (const float*)d_in[10];
    const float* b_hh = (const float*)d_in[11];
    const float* Wr1  = (const float*)d_in[12];
    const float* br1  = (const float*)d_in[13];
    const float* Wr2  = (const float*)d_in[14];
    const float* br2  = (const float*)d_in[15];
    const float* Wr3  = (const float*)d_in[16];
    const float* br3  = (const float*)d_in[17];
    float* outp = (float*)d_out;

    float* ws = (float*)d_ws;

    static int coop_attr = -1;
    if (coop_attr < 0) {
        int v = 0;
        if (hipDeviceGetAttribute(&v, hipDeviceAttributeCooperativeLaunch, 0) != hipSuccess) v = 0;
        coop_attr = v;
    }

    float* aP    = ws;                       // 6 * 32768 floats (slot 0 unused)
    int*   flags = (int*)(ws + 6*32768);     // 512 * FSTR ints = 64 KB
    const size_t FLAG_BYTES = 512u * FSTR * sizeof(int);

    hipError_t lerr = hipErrorUnknown;
    if (coop_attr) {
        hipError_t merr = hipMemsetAsync((void*)flags, 0, FLAG_BYTES, stream);
        if (merr == hipSuccess) {
            void* args[] = {
                (void*)&J, (void*)&b, (void*)&W1, (void*)&b1, (void*)&W2, (void*)&b2,
                (void*)&W3, (void*)&b3, (void*)&W_ih, (void*)&b_ih, (void*)&W_hh, (void*)&b_hh,
                (void*)&Wr1, (void*)&br1, (void*)&Wr2, (void*)&br2, (void*)&Wr3, (void*)&br3,
                (void*)&aP, (void*)&flags, (void*)&outp
            };
            lerr = hipLaunchCooperativeKernel(reinterpret_cast<void*>(fused3_kernel),
                                              dim3(NN/2), dim3(512), args, 0, stream);
        }
    }
    if (lerr == hipSuccess) return;
    (void)hipGetLastError();   // clear error state before fallback

    // --- fallback: proven multi-launch path ---
    float* Jt   = ws + 262144;
    float* aG0  = Jt + 262144;
    float* aG1  = aG0 + 32768;
    float* cG0  = aG1 + 32768;
    float* cG1  = cG0 + 32768;
    float* hA   = cG1 + 32768;
    float* hB   = hA + 8192;
    float* wJ   = hB + 8192;
    float* wbi  = wJ + 64;
    float* wbj  = wbi + 64;
    float* W1hiT = wbj + 64;
    float* W1hjT = W1hiT + 1024;
    unsigned short* W2bf = (unsigned short*)(W1hjT + 1024);

    hipLaunchKernelGGL(init_kernel, dim3(130), dim3(256), 0, stream,
                       J, b, W1, b1, W2, Jt, aG0, cG0, hA, wJ, wbi, wbj, W1hiT, W1hjT, W2bf);

    float* aIn = aG0; float* aOut = aG1;
    float* cIn = cG0; float* cOut = cG1;
    float* hI  = hA;  float* hO  = hB;
    for (int t = 0; t < NSTEPS; ++t) {
        hipLaunchKernelGGL(edge_kernel, dim3(512), dim3(256), 0, stream,
            Jt, aIn, cIn, hI, aOut, cOut, hO, W2bf, wJ, b2, W3, b3,
            W_ih, b_ih, W_hh, b_hh, W1hiT, W1hjT, wbi, wbj, b, b1,
            Wr1, br1, Wr2, br2, Wr3, br3, outp, (t == NSTEPS-1) ? 1 : 0);
        float* tmp;
        tmp = aIn; aIn = aOut; aOut = tmp;
        tmp = cIn; cIn = cOut; cOut = tmp;
        tmp = hI;  hI  = hO;  hO  = tmp;
    }
}

// Round 5
// 171.622 us; speedup vs baseline: 2.7661x; 1.2317x over previous
//
#include <hip/hip_runtime.h>
#include <hip/hip_bf16.h>

#define NN 512
#define NSTEPS 5
#define FSTR 32   // flag stride in ints: 128 B/flag, one line each

typedef __attribute__((ext_vector_type(8))) short short8;
typedef __attribute__((ext_vector_type(4))) float floatx4;

static __device__ __forceinline__ unsigned short f2bf(float f) {
    union { float f; unsigned u; } x; x.f = f;
    unsigned r = x.u + 0x7fffu + ((x.u >> 16) & 1u);
    return (unsigned short)(r >> 16);
}

static __device__ __forceinline__ unsigned pk2bf(float a, float b) {
    __hip_bfloat162 h = __float22bfloat162_rn(make_float2(a, b));
    return *reinterpret_cast<unsigned*>(&h);
}

// ============================================================================
// Barrier-free fused kernel: 256 blocks x 512 threads, 2 nodes per block.
// PLAIN (non-cooperative) launch: 1 block/CU on 256 CUs -> all blocks resident
// immediately on an exclusively-held chip; sync is via workspace flags only.
// (hipLaunchCooperativeKernel measured a constant ~112us runtime overhead in
//  this harness across R2/R3/R4 -- identical kernels, plain launch avoids it.)
// Cross-block exchange via per-node ready flags + 5 distinct panel buffers:
//   producer: agent-scope stores of its 64-float row, vmcnt(0), flag[j]=s.
//   consumer: parallel-polls the 8 flags of the rows it reads (one round-trip
//             when already set), then plain cached vector loads (buffer s is
//             write-once-then-read-only -> no stale-line hazard).
// ============================================================================
__global__ __launch_bounds__(512, 2) void fused3_kernel(
    const float* __restrict__ J, const float* __restrict__ b,
    const float* __restrict__ W1, const float* __restrict__ b1,
    const float* __restrict__ W2, const float* __restrict__ b2,
    const float* __restrict__ W3, const float* __restrict__ b3,
    const float* __restrict__ W_ih, const float* __restrict__ b_ih,
    const float* __restrict__ W_hh, const float* __restrict__ b_hh,
    const float* __restrict__ Wr1, const float* __restrict__ br1,
    const float* __restrict__ Wr2, const float* __restrict__ br2,
    const float* __restrict__ Wr3, const float* __restrict__ br3,
    float* __restrict__ aP, int* __restrict__ flag,
    float* __restrict__ out)
{
    const int tid = threadIdx.x;
    const int bid = blockIdx.x;
    const int nd = tid >> 8;          // which of the block's 2 nodes
    const int tl = tid & 255;         // local tid within node group
    const int j  = bid * 2 + nd;
    const int l  = tid & 63, w4 = tl >> 6;
    const int m  = l & 15,  q  = l >> 4;

    __shared__ float smW1hi[64][16], smW1hj[64][16];
    __shared__ float smC[2][64], smAbias[2][64], smCbias[2][64];
    __shared__ float smWave[2][4][64], smMacc[2][64];
    __shared__ float smGin[2][48], smGi[2][48], smGh[2][48];
    __shared__ float smH[2][16], smY[2][64], smR[2][2];

    // Drop stale clean L1/L2 lines of the workspace (harness poison-fill).
    __builtin_amdgcn_fence(__ATOMIC_ACQUIRE, "agent");

    // ---- publish a^1 (bias-only, h0=0) + per-node meta ----
    if (tid < 128) {
        int nd0 = tid >> 6, o = tid & 63;
        int j0 = bid*2 + nd0;
        float bj0 = b[j0];
        const float* w1r = W1 + o*35;
        float ab = bj0 * w1r[33];
        smAbias[nd0][o] = ab;
        float cb = bj0 * w1r[34] + b1[o];
        smCbias[nd0][o] = cb;
        smC[nd0][o] = cb;                  // h0 = 0 -> c0 bias-only
        __hip_atomic_store(&aP[32768 + j0*64 + o], ab,
                           __ATOMIC_RELAXED, __HIP_MEMORY_SCOPE_AGENT);
    }
    if (tid < 128) {   // waves 0,1 whole: wave-uniform, per-wave vmcnt
        asm volatile("s_waitcnt vmcnt(0)" ::: "memory");
        if ((tid & 63) == 0)
            __hip_atomic_store(&flag[(bid*2 + (tid >> 6))*FSTR], 1,
                               __ATOMIC_RELAXED, __HIP_MEMORY_SCOPE_AGENT);
    }
    if (tid >= 128 && tid < 160) {
        int nd0 = (tid - 128) >> 4, o = (tid - 128) & 15;
        smH[nd0][o] = 0.f;
    }
    if (tid < 64) {
        const float* w1r = W1 + tid*35;
        #pragma unroll
        for (int s0 = 0; s0 < 16; ++s0) {
            smW1hi[tid][s0] = w1r[s0];
            smW1hj[tid][s0] = w1r[16 + s0];
        }
    }

    // J column for this node (i = w4*128 + c8*16 + m), once
    float Jr[8];
    #pragma unroll
    for (int c8 = 0; c8 < 8; ++c8)
        Jr[c8] = J[(w4*128 + c8*16 + m)*512 + j];

    // wJ vectors for this lane's o-set
    floatx4 wva, wvb, wvc, wvd;
    #pragma unroll
    for (int e = 0; e < 4; ++e) {
        wva[e] = W1[(q*8 + e)*35 + 32];
        wvb[e] = W1[(q*8 + 4 + e)*35 + 32];
        wvc[e] = W1[(32 + q*8 + e)*35 + 32];
        wvd[e] = W1[(32 + q*8 + 4 + e)*35 + 32];
    }

    // W2 B-fragments, in-register, once. B[k][n] = W2[n][k]
    short8 bfw[4][2];
    #pragma unroll
    for (int nt = 0; nt < 4; ++nt) {
        #pragma unroll
        for (int ks = 0; ks < 2; ++ks) {
            union { short8 s; unsigned short us[8]; } tpk;
            int n = nt*16 + m;
            #pragma unroll
            for (int jj = 0; jj < 8; ++jj)
                tpk.us[jj] = f2bf(W2[n*64 + ks*32 + q*8 + jj]);
            bfw[nt][ks] = tpk.s;
        }
    }
    float b2n[4];
    #pragma unroll
    for (int nt = 0; nt < 4; ++nt) b2n[nt] = b2[nt*16 + m];

    __syncthreads();   // smC / smW1 / smH ready

    for (int t = 0; t < NSTEPS; ++t) {
        const int last = (t == NSTEPS - 1);
        const int s = t + 1;               // panel generation consumed now

        floatx4 cva, cvb, cvc, cvd;
        #pragma unroll
        for (int e = 0; e < 4; ++e) {
            cva[e] = smC[nd][q*8 + e];
            cvb[e] = smC[nd][q*8 + 4 + e];
            cvc[e] = smC[nd][32 + q*8 + e];
            cvd[e] = smC[nd][32 + q*8 + 4 + e];
        }

        // wait for the 8 rows this lane reads -- PARALLEL poll (independent
        // loads, min-reduce): one memory round-trip when already satisfied.
        {
            const int rbase = w4*128 + m;
            for (;;) {
                int f0 = __hip_atomic_load(&flag[(rbase +   0)*FSTR], __ATOMIC_RELAXED, __HIP_MEMORY_SCOPE_AGENT);
                int f1 = __hip_atomic_load(&flag[(rbase +  16)*FSTR], __ATOMIC_RELAXED, __HIP_MEMORY_SCOPE_AGENT);
                int f2 = __hip_atomic_load(&flag[(rbase +  32)*FSTR], __ATOMIC_RELAXED, __HIP_MEMORY_SCOPE_AGENT);
                int f3 = __hip_atomic_load(&flag[(rbase +  48)*FSTR], __ATOMIC_RELAXED, __HIP_MEMORY_SCOPE_AGENT);
                int f4 = __hip_atomic_load(&flag[(rbase +  64)*FSTR], __ATOMIC_RELAXED, __HIP_MEMORY_SCOPE_AGENT);
                int f5 = __hip_atomic_load(&flag[(rbase +  80)*FSTR], __ATOMIC_RELAXED, __HIP_MEMORY_SCOPE_AGENT);
                int f6 = __hip_atomic_load(&flag[(rbase +  96)*FSTR], __ATOMIC_RELAXED, __HIP_MEMORY_SCOPE_AGENT);
                int f7 = __hip_atomic_load(&flag[(rbase + 112)*FSTR], __ATOMIC_RELAXED, __HIP_MEMORY_SCOPE_AGENT);
                int mn = min(min(min(f0, f1), min(f2, f3)),
                             min(min(f4, f5), min(f6, f7)));
                if (mn >= s) break;
                __builtin_amdgcn_s_sleep(1);
            }
        }
        asm volatile("" ::: "memory");     // no hoisting panel loads above poll

        floatx4 acc[4];
        #pragma unroll
        for (int nt = 0; nt < 4; ++nt) acc[nt] = (floatx4){0.f,0.f,0.f,0.f};

        const floatx4* a4 = (const floatx4*)(aP + (size_t)s*32768);

        for (int c8 = 0; c8 < 8; ++c8) {
            int i = w4*128 + c8*16 + m;
            float Jij = Jr[c8];
            floatx4 av0 = a4[i*16 + q*2],     av1 = a4[i*16 + q*2 + 1];
            floatx4 av2 = a4[i*16 + 8 + q*2], av3 = a4[i*16 + 8 + q*2 + 1];
            floatx4 x0, x1, x2, x3;
            #pragma unroll
            for (int e = 0; e < 4; ++e) {
                x0[e] = fmaxf(fmaf(Jij, wva[e], av0[e]) + cva[e], 0.f);
                x1[e] = fmaxf(fmaf(Jij, wvb[e], av1[e]) + cvb[e], 0.f);
                x2[e] = fmaxf(fmaf(Jij, wvc[e], av2[e]) + cvc[e], 0.f);
                x3[e] = fmaxf(fmaf(Jij, wvd[e], av3[e]) + cvd[e], 0.f);
            }
            union { short8 s; unsigned u[4]; } fa0, fa1;
            fa0.u[0] = pk2bf(x0[0], x0[1]); fa0.u[1] = pk2bf(x0[2], x0[3]);
            fa0.u[2] = pk2bf(x1[0], x1[1]); fa0.u[3] = pk2bf(x1[2], x1[3]);
            fa1.u[0] = pk2bf(x2[0], x2[1]); fa1.u[1] = pk2bf(x2[2], x2[3]);
            fa1.u[2] = pk2bf(x3[0], x3[1]); fa1.u[3] = pk2bf(x3[2], x3[3]);
            #pragma unroll
            for (int nt = 0; nt < 4; ++nt) {
                floatx4 d = {0.f,0.f,0.f,0.f};
                d = __builtin_amdgcn_mfma_f32_16x16x32_bf16(fa0.s, bfw[nt][0], d, 0, 0, 0);
                d = __builtin_amdgcn_mfma_f32_16x16x32_bf16(fa1.s, bfw[nt][1], d, 0, 0, 0);
                #pragma unroll
                for (int r = 0; r < 4; ++r)
                    acc[nt][r] += fmaxf(d[r] + b2n[nt], 0.f);
            }
        }

        // reduce rows within wave, stage h into smGin
        #pragma unroll
        for (int nt = 0; nt < 4; ++nt) {
            float v = acc[nt][0] + acc[nt][1] + acc[nt][2] + acc[nt][3];
            v += __shfl_xor(v, 16);
            v += __shfl_xor(v, 32);
            if (l < 16) smWave[nd][w4][nt*16 + l] = v;
        }
        if (tl < 16) smGin[nd][tl] = smH[nd][tl];
        __syncthreads();
        if (tl < 64) smMacc[nd][tl] = smWave[nd][0][tl] + smWave[nd][1][tl]
                                    + smWave[nd][2][tl] + smWave[nd][3][tl];
        __syncthreads();

        // msg = W3 @ macc + 512*b3
        {
            int o = tl >> 3, p = tl & 7;
            const floatx4* W3v = (const floatx4*)W3;
            floatx4 wv0 = W3v[o*16 + p*2], wv1 = W3v[o*16 + p*2 + 1];
            float part = 0.f;
            #pragma unroll
            for (int e = 0; e < 4; ++e) {
                part = fmaf(wv0[e], smMacc[nd][p*8 + e], part);
                part = fmaf(wv1[e], smMacc[nd][p*8 + 4 + e], part);
            }
            part += __shfl_xor(part, 1);
            part += __shfl_xor(part, 2);
            part += __shfl_xor(part, 4);
            if (p == 0) smGin[nd][16 + o] = part + 512.f * b3[o];
        }
        __syncthreads();

        // GRU gates
        if (tl < 192) {
            int o = tl >> 2, p = tl & 3;
            const floatx4* Wv = (const floatx4*)W_ih;
            floatx4 w0 = Wv[o*12 + p*3], w1 = Wv[o*12 + p*3 + 1], w2 = Wv[o*12 + p*3 + 2];
            int k0 = p*12;
            float part = 0.f;
            #pragma unroll
            for (int e = 0; e < 4; ++e) {
                part = fmaf(w0[e], smGin[nd][k0 + e], part);
                part = fmaf(w1[e], smGin[nd][k0 + 4 + e], part);
                part = fmaf(w2[e], smGin[nd][k0 + 8 + e], part);
            }
            part += __shfl_xor(part, 1);
            part += __shfl_xor(part, 2);
            if (p == 0) smGi[nd][o] = part + b_ih[o];
        } else if (tl < 240) {
            int o = tl - 192;
            const floatx4* Wv = (const floatx4*)W_hh;
            floatx4 w0 = Wv[o*4], w1 = Wv[o*4+1], w2 = Wv[o*4+2], w3 = Wv[o*4+3];
            float s2 = b_hh[o];
            #pragma unroll
            for (int e = 0; e < 4; ++e) {
                s2 = fmaf(w0[e], smGin[nd][e],      s2);
                s2 = fmaf(w1[e], smGin[nd][4 + e],  s2);
                s2 = fmaf(w2[e], smGin[nd][8 + e],  s2);
                s2 = fmaf(w3[e], smGin[nd][12 + e], s2);
            }
            smGh[nd][o] = s2;
        }
        __syncthreads();

        if (tl < 16) {
            float r = 1.f / (1.f + __expf(-(smGi[nd][tl] + smGh[nd][tl])));
            float z = 1.f / (1.f + __expf(-(smGi[nd][16+tl] + smGh[nd][16+tl])));
            float n = tanhf(smGi[nd][32+tl] + r * smGh[nd][32+tl]);
            float hn = (1.f - z)*n + z*smGin[nd][tl];
            smH[nd][tl] = hn;
        }
        __syncthreads();

        if (!last) {
            if (tl < 128) {
                int o = tl & 63, sel = tl >> 6;
                const floatx4* Wv = (const floatx4*)(sel ? &smW1hj[0][0] : &smW1hi[0][0]);
                floatx4 w0 = Wv[o*4], w1 = Wv[o*4+1], w2 = Wv[o*4+2], w3 = Wv[o*4+3];
                float sacc = 0.f;
                #pragma unroll
                for (int e = 0; e < 4; ++e) {
                    sacc = fmaf(w0[e], smH[nd][e],      sacc);
                    sacc = fmaf(w1[e], smH[nd][4 + e],  sacc);
                    sacc = fmaf(w2[e], smH[nd][8 + e],  sacc);
                    sacc = fmaf(w3[e], smH[nd][12 + e], sacc);
                }
                if (sel == 0) {
                    // publish next panel row straight to the coherent point
                    __hip_atomic_store(&aP[(size_t)(s+1)*32768 + j*64 + o],
                                       sacc + smAbias[nd][o],
                                       __ATOMIC_RELAXED, __HIP_MEMORY_SCOPE_AGENT);
                } else {
                    smC[nd][o] = sacc + smCbias[nd][o];
                }
            }
            if (tl < 64) {   // the producer wave: per-wave vmcnt then set flag
                asm volatile("s_waitcnt vmcnt(0)" ::: "memory");
                if (tl == 0)
                    __hip_atomic_store(&flag[j*FSTR], s + 1,
                                       __ATOMIC_RELAXED, __HIP_MEMORY_SCOPE_AGENT);
            }
            __syncthreads();   // protects smC for next iteration's reads
        } else {
            if (tl < 64) {
                const floatx4* Wv = (const floatx4*)Wr1;
                floatx4 w0 = Wv[tl*4], w1 = Wv[tl*4+1], w2 = Wv[tl*4+2], w3 = Wv[tl*4+3];
                float sacc = br1[tl];
                #pragma unroll
                for (int e = 0; e < 4; ++e) {
                    sacc = fmaf(w0[e], smH[nd][e],      sacc);
                    sacc = fmaf(w1[e], smH[nd][4 + e],  sacc);
                    sacc = fmaf(w2[e], smH[nd][8 + e],  sacc);
                    sacc = fmaf(w3[e], smH[nd][12 + e], sacc);
                }
                smY[nd][tl] = fmaxf(sacc, 0.f);
            }
            __syncthreads();
            {   // y2: 64 outputs x 64 inputs, 4 threads per output
                int o = tl >> 2, p = tl & 3;
                const floatx4* Wv = (const floatx4*)Wr2;
                floatx4 w0 = Wv[o*16 + p*4],     w1 = Wv[o*16 + p*4 + 1];
                floatx4 w2 = Wv[o*16 + p*4 + 2], w3 = Wv[o*16 + p*4 + 3];
                int k0 = p*16;
                float part = 0.f;
                #pragma unroll
                for (int e = 0; e < 4; ++e) {
                    part = fmaf(w0[e], smY[nd][k0 + e],      part);
                    part = fmaf(w1[e], smY[nd][k0 + 4 + e],  part);
                    part = fmaf(w2[e], smY[nd][k0 + 8 + e],  part);
                    part = fmaf(w3[e], smY[nd][k0 + 12 + e], part);
                }
                part += __shfl_xor(part, 1);
                part += __shfl_xor(part, 2);
                __syncthreads();
                if (p == 0) smY[nd][o] = fmaxf(part + br2[o], 0.f);
            }
            __syncthreads();
            if (tl < 128) {
                int ot = tl >> 6, p = tl & 63;
                float part = Wr3[ot*64 + p] * smY[nd][p];
                part += __shfl_xor(part, 1);
                part += __shfl_xor(part, 2);
                part += __shfl_xor(part, 4);
                part += __shfl_xor(part, 8);
                part += __shfl_xor(part, 16);
                part += __shfl_xor(part, 32);
                if (p == 0) smR[nd][ot] = part + br3[ot];
            }
            __syncthreads();
            if (tl == 0) {
                float e0 = 1.f/(1.f + __expf(-smR[nd][0]));
                float e1 = 1.f/(1.f + __expf(-smR[nd][1]));
                float tsum = e0 + e1;
                out[j*2]     = e0/tsum;
                out[j*2 + 1] = e1/tsum;
            }
        }
    }
}

extern "C" void kernel_launch(void* const* d_in, const int* in_sizes, int n_in,
                              void* d_out, int out_size, void* d_ws, size_t ws_size,
                              hipStream_t stream)
{
    const float* J    = (const float*)d_in[0];
    const float* b    = (const float*)d_in[1];
    const float* W1   = (const float*)d_in[2];
    const float* b1   = (const float*)d_in[3];
    const float* W2   = (const float*)d_in[4];
    const float* b2   = (const float*)d_in[5];
    const float* W3   = (const float*)d_in[6];
    const float* b3   = (const float*)d_in[7];
    const float* W_ih = (const float*)d_in[8];
    const float* b_ih = (const float*)d_in[9];
    const float* W_hh = (const float*)d_in[10];
    const float* b_hh = (const float*)d_in[11];
    const float* Wr1  = (const float*)d_in[12];
    const float* br1  = (const float*)d_in[13];
    const float* Wr2  = (const float*)d_in[14];
    const float* br2  = (const float*)d_in[15];
    const float* Wr3  = (const float*)d_in[16];
    const float* br3  = (const float*)d_in[17];
    float* outp = (float*)d_out;

    float* ws = (float*)d_ws;
    float* aP    = ws;                       // 6 * 32768 floats (slot 0 unused)
    int*   flags = (int*)(ws + 6*32768);     // 512 * FSTR ints = 64 KB
    const size_t FLAG_BYTES = 512u * FSTR * sizeof(int);

    // zero the barrier flags (epochs start at 1); stream-ordered, graph-safe
    hipMemsetAsync((void*)flags, 0, FLAG_BYTES, stream);

    // PLAIN launch: 256 blocks x 512 threads = 1 block/CU, all co-resident.
    hipLaunchKernelGGL(fused3_kernel, dim3(NN/2), dim3(512), 0, stream,
        J, b, W1, b1, W2, b2, W3, b3, W_ih, b_ih, W_hh, b_hh,
        Wr1, br1, Wr2, br2, Wr3, br3, aP, flags, outp);
}